// Round 1
// baseline (259.320 us; speedup 1.0000x reference)
//
#include <hip/hip_runtime.h>

#define B  4
#define C  64
#define C8 8
#define DD 16
#define H  64
#define W  64
#define EPSV 1e-5f
// k = int(0.6*64) = 38 -> threshold = 38th largest = ascending index 64-38 = 26

// ---------------- Kernel 1: depthwise 5x5 conv (over H,W) + BN1 + SiLU -> y1 (d_ws)
__global__ __launch_bounds__(256) void dwconv_kernel(
    const float* __restrict__ x, const float* __restrict__ w_dw,
    const float* __restrict__ g1, const float* __restrict__ be1,
    const float* __restrict__ mu1, const float* __restrict__ va1,
    float* __restrict__ y1)
{
    // one block per (b, d, c) slice of 64x64 (16 KB, L1-resident)
    const int blk = blockIdx.x;
    const int c = blk & 63;
    const int d = (blk >> 6) & 15;
    const int b = blk >> 10;

    // conv weights for this channel (uniform -> scalar loads)
    float wk[25];
#pragma unroll
    for (int i = 0; i < 25; ++i) wk[i] = w_dw[c * 25 + i];
    const float scale = g1[c] * rsqrtf(va1[c] + EPSV);
    const float shift = be1[c] - mu1[c] * scale;

    const int tid = threadIdx.x;
    const int wq = (tid & 15) * 4;      // output cols wq..wq+3
    const long base = ((long)(b * C + c) * DD + d) * (H * W);

#pragma unroll
    for (int p = 0; p < 4; ++p) {
        const int h = (tid >> 4) + p * 16;
        float acc0 = 0.f, acc1 = 0.f, acc2 = 0.f, acc3 = 0.f;
#pragma unroll
        for (int j = 0; j < 5; ++j) {
            const int r = h + j - 2;
            if (r >= 0 && r < H) {
                const float4* rowp = (const float4*)(x + base + r * W);
                const int q = wq >> 2;
                float4 v0 = (wq >= 4)  ? rowp[q - 1] : make_float4(0.f, 0.f, 0.f, 0.f);
                float4 v1 = rowp[q];
                float4 v2 = (wq <= 56) ? rowp[q + 1] : make_float4(0.f, 0.f, 0.f, 0.f);
                float vals[12] = {v0.x, v0.y, v0.z, v0.w,
                                  v1.x, v1.y, v1.z, v1.w,
                                  v2.x, v2.y, v2.z, v2.w};
#pragma unroll
                for (int dw = 0; dw < 5; ++dw) {
                    const float kw = wk[j * 5 + dw];
                    acc0 += kw * vals[0 + 2 + dw];
                    acc1 += kw * vals[1 + 2 + dw];
                    acc2 += kw * vals[2 + 2 + dw];
                    acc3 += kw * vals[3 + 2 + dw];
                }
            }
        }
        float4 o;
        {
            float v = acc0 * scale + shift; o.x = v * (1.f / (1.f + __expf(-v)));
            v = acc1 * scale + shift;       o.y = v * (1.f / (1.f + __expf(-v)));
            v = acc2 * scale + shift;       o.z = v * (1.f / (1.f + __expf(-v)));
            v = acc3 * scale + shift;       o.w = v * (1.f / (1.f + __expf(-v)));
        }
        *(float4*)(y1 + base + h * W + wq) = o;
    }
}

// ---------------- Kernel 2: pw1 + BN2 + SiLU + pw2, attn = y1*y2, top-k mask, epilogue
__global__ __launch_bounds__(256) void fuse_kernel(
    const float* __restrict__ x, const float* __restrict__ y1,
    const float* __restrict__ w1, const float* __restrict__ b1,
    const float* __restrict__ g2, const float* __restrict__ be2,
    const float* __restrict__ mu2, const float* __restrict__ va2,
    const float* __restrict__ w2, const float* __restrict__ b2,
    const float* __restrict__ alphap, float* __restrict__ out)
{
    const int gid = blockIdx.x * 256 + threadIdx.x;  // one thread = one (b,d,h,w)
    const int b = gid >> 16;          // / (D*H*W = 65536)
    const int r = gid & 65535;        // d*4096 + h*64 + w
    const long base = (long)b * (C * 65536) + r;   // channel stride = 65536

    // pw1: s1[o] = sum_c w1[o][c] * x[c]
    float s1[C8];
#pragma unroll
    for (int o = 0; o < C8; ++o) s1[o] = 0.f;
#pragma unroll
    for (int c = 0; c < C; ++c) {
        const float xc = x[base + (long)c * 65536];
#pragma unroll
        for (int o = 0; o < C8; ++o) s1[o] += w1[o * C + c] * xc;
    }
    // + b_pw1, BN2, SiLU
    float hh[C8];
#pragma unroll
    for (int o = 0; o < C8; ++o) {
        const float sc = g2[o] * rsqrtf(va2[o] + EPSV);
        const float v = (s1[o] + b1[o] - mu2[o]) * sc + be2[o];
        hh[o] = v * (1.f / (1.f + __expf(-v)));
    }

    // attn[c] = y1[c] * (pw2 row c . hh + b2[c]); keep a copy for sorting
    float a[C], t[C];
#pragma unroll
    for (int c = 0; c < C; ++c) {
        float y2 = b2[c];
#pragma unroll
        for (int o = 0; o < C8; ++o) y2 += w2[c * C8 + o] * hh[o];
        const float av = y1[base + (long)c * 65536] * y2;
        a[c] = av;
        t[c] = av;
    }

    // in-register bitonic sort (ascending) of 64 values
#pragma unroll
    for (int k = 2; k <= 64; k <<= 1) {
#pragma unroll
        for (int j = k >> 1; j > 0; j >>= 1) {
#pragma unroll
            for (int i = 0; i < 64; ++i) {
                const int l = i ^ j;
                if (l > i) {
                    const float u = t[i], v = t[l];
                    const float mn = fminf(u, v), mx = fmaxf(u, v);
                    if ((i & k) == 0) { t[i] = mn; t[l] = mx; }
                    else              { t[i] = mx; t[l] = mn; }
                }
            }
        }
    }
    const float thr = t[26];          // 38th largest of 64
    const float alpha = alphap[0];

#pragma unroll
    for (int c = 0; c < C; ++c) {
        const float xc = x[base + (long)c * 65536];   // L3-resident re-read
        const float av = a[c];
        out[base + (long)c * 65536] = xc + ((av >= thr) ? alpha * av : 0.f);
    }
}

extern "C" void kernel_launch(void* const* d_in, const int* in_sizes, int n_in,
                              void* d_out, int out_size, void* d_ws, size_t ws_size,
                              hipStream_t stream) {
    const float* x    = (const float*)d_in[0];
    const float* w_dw = (const float*)d_in[1];
    const float* g1   = (const float*)d_in[2];
    const float* be1  = (const float*)d_in[3];
    const float* mu1  = (const float*)d_in[4];
    const float* va1  = (const float*)d_in[5];
    const float* w1   = (const float*)d_in[6];
    const float* b1   = (const float*)d_in[7];
    const float* g2   = (const float*)d_in[8];
    const float* be2  = (const float*)d_in[9];
    const float* mu2  = (const float*)d_in[10];
    const float* va2  = (const float*)d_in[11];
    const float* w2   = (const float*)d_in[12];
    const float* b2   = (const float*)d_in[13];
    const float* alp  = (const float*)d_in[14];
    float* out = (float*)d_out;
    float* y1  = (float*)d_ws;   // needs B*C*DD*H*W*4 = 16 MiB of scratch

    dwconv_kernel<<<B * DD * C, 256, 0, stream>>>(x, w_dw, g1, be1, mu1, va1, y1);
    fuse_kernel<<<(B * DD * H * W) / 256, 256, 0, stream>>>(
        x, y1, w1, b1, g2, be2, mu2, va2, w2, b2, alp, out);
}

// Round 2
// 237.766 us; speedup vs baseline: 1.0907x; 1.0907x over previous
//
#include <hip/hip_runtime.h>

#define B  4
#define C  64
#define C8 8
#define DD 16
#define H  64
#define W  64
#define EPSV 1e-5f
// k = int(0.6*64) = 38 -> threshold = 38th largest = ascending index 26

// ---------------- Kernel 1: depthwise 5x5 conv (over H,W) + BN1 + SiLU -> y1 (d_ws)
// Each thread computes a 4h x 8w output patch: 8 input rows x 4 float4 loads
// = 32 loads for 32 outputs (was 3.75 loads/output, now 1.0).
// Block = 256 threads = 2 channel-slices x 128 threads.
__global__ __launch_bounds__(256) void dwconv_kernel(
    const float* __restrict__ x, const float* __restrict__ w_dw,
    const float* __restrict__ g1, const float* __restrict__ be1,
    const float* __restrict__ mu1, const float* __restrict__ va1,
    float* __restrict__ y1)
{
    const int blk = blockIdx.x;            // 2048 blocks
    const int half = threadIdx.x >> 7;     // 0/1 -> which channel of the pair
    const int t = threadIdx.x & 127;
    const int cpair = blk & 31;
    const int d = (blk >> 5) & 15;
    const int b = blk >> 9;
    const int c = cpair * 2 + half;

    float wk[25];
#pragma unroll
    for (int i = 0; i < 25; ++i) wk[i] = w_dw[c * 25 + i];
    const float scale = g1[c] * rsqrtf(va1[c] + EPSV);
    const float shift = be1[c] - mu1[c] * scale;

    const int w8 = (t & 7) * 8;            // output cols w8..w8+7
    const int h4 = (t >> 3) * 4;           // output rows h4..h4+3
    const long base = ((long)(b * C + c) * DD + d) * (H * W);

    float acc[4][8];
#pragma unroll
    for (int i = 0; i < 4; ++i)
#pragma unroll
        for (int ow = 0; ow < 8; ++ow) acc[i][ow] = 0.f;

#pragma unroll
    for (int j = 0; j < 8; ++j) {          // input row r = h4 + j - 2
        const int r = h4 + j - 2;
        if (r >= 0 && r < H) {
            const float4* rowp = (const float4*)(x + base + r * W);
            const int q = w8 >> 2;
            const float4 z = make_float4(0.f, 0.f, 0.f, 0.f);
            float4 v0 = (w8 > 0)  ? rowp[q - 1] : z;
            float4 v1 = rowp[q];
            float4 v2 = rowp[q + 1];
            float4 v3 = (w8 < 56) ? rowp[q + 2] : z;
            // vals[v] = x[row r, col w8-4+v]
            float vals[16] = {v0.x, v0.y, v0.z, v0.w,
                              v1.x, v1.y, v1.z, v1.w,
                              v2.x, v2.y, v2.z, v2.w,
                              v3.x, v3.y, v3.z, v3.w};
#pragma unroll
            for (int i = 0; i < 4; ++i) {
                if (i <= j && (j - i) <= 4) {   // kernel row kr = j - i
                    const int kr = j - i;
#pragma unroll
                    for (int dw = 0; dw < 5; ++dw) {
                        const float kw = wk[kr * 5 + dw];
#pragma unroll
                        for (int ow = 0; ow < 8; ++ow)
                            acc[i][ow] += kw * vals[ow + dw + 2];
                    }
                }
            }
        }
    }

#pragma unroll
    for (int i = 0; i < 4; ++i) {
        const int h = h4 + i;
        float o[8];
#pragma unroll
        for (int ow = 0; ow < 8; ++ow) {
            const float v = acc[i][ow] * scale + shift;
            o[ow] = v * (1.f / (1.f + __expf(-v)));
        }
        *(float4*)(y1 + base + h * W + w8)     = make_float4(o[0], o[1], o[2], o[3]);
        *(float4*)(y1 + base + h * W + w8 + 4) = make_float4(o[4], o[5], o[6], o[7]);
    }
}

// ---------------- Kernel 2: pw1 + BN2 + SiLU + pw2, attn = y1*y2, top-k mask, epilogue
// Register-lean: only t[64] (sort array) + hh[8] live; attn recomputed in the
// epilogue from hh + a y1 re-read (L2-hot).
__global__ __launch_bounds__(256) void fuse_kernel(
    const float* __restrict__ x, const float* __restrict__ y1,
    const float* __restrict__ w1, const float* __restrict__ b1,
    const float* __restrict__ g2, const float* __restrict__ be2,
    const float* __restrict__ mu2, const float* __restrict__ va2,
    const float* __restrict__ w2, const float* __restrict__ b2,
    const float* __restrict__ alphap, float* __restrict__ out)
{
    const int gid = blockIdx.x * 256 + threadIdx.x;  // one thread = one (b,d,h,w)
    const int b = gid >> 16;          // / (D*H*W = 65536)
    const int r = gid & 65535;        // d*4096 + h*64 + w
    const long base = (long)b * (C * 65536) + r;   // channel stride = 65536

    // pw1: s1[o] = sum_c w1[o][c] * x[c]
    float s1[C8];
#pragma unroll
    for (int o = 0; o < C8; ++o) s1[o] = 0.f;
#pragma unroll
    for (int c = 0; c < C; ++c) {
        const float xc = x[base + (long)c * 65536];
#pragma unroll
        for (int o = 0; o < C8; ++o) s1[o] += w1[o * C + c] * xc;
    }
    // + b_pw1, BN2, SiLU
    float hh[C8];
#pragma unroll
    for (int o = 0; o < C8; ++o) {
        const float sc = g2[o] * rsqrtf(va2[o] + EPSV);
        const float v = (s1[o] + b1[o] - mu2[o]) * sc + be2[o];
        hh[o] = v * (1.f / (1.f + __expf(-v)));
    }

    // attn[c] -> t[c] (will be destroyed by the sort; recomputed in epilogue)
    float t[C];
#pragma unroll
    for (int c = 0; c < C; ++c) {
        float y2 = b2[c];
#pragma unroll
        for (int o = 0; o < C8; ++o) y2 += w2[c * C8 + o] * hh[o];
        t[c] = y1[base + (long)c * 65536] * y2;
    }

    // in-register bitonic sort (ascending) of 64 values
#pragma unroll
    for (int k = 2; k <= 64; k <<= 1) {
#pragma unroll
        for (int j = k >> 1; j > 0; j >>= 1) {
#pragma unroll
            for (int i = 0; i < 64; ++i) {
                const int l = i ^ j;
                if (l > i) {
                    const float u = t[i], v = t[l];
                    const float mn = fminf(u, v), mx = fmaxf(u, v);
                    if ((i & k) == 0) { t[i] = mn; t[l] = mx; }
                    else              { t[i] = mx; t[l] = mn; }
                }
            }
        }
    }
    const float thr = t[26];          // 38th largest of 64
    const float alpha = alphap[0];

    // epilogue: recompute attn[c] exactly (same FMA order as above), mask, add
#pragma unroll
    for (int c = 0; c < C; ++c) {
        float y2 = b2[c];
#pragma unroll
        for (int o = 0; o < C8; ++o) y2 += w2[c * C8 + o] * hh[o];
        const float av = y1[base + (long)c * 65536] * y2;
        const float xc = x[base + (long)c * 65536];
        out[base + (long)c * 65536] = xc + ((av >= thr) ? alpha * av : 0.f);
    }
}

extern "C" void kernel_launch(void* const* d_in, const int* in_sizes, int n_in,
                              void* d_out, int out_size, void* d_ws, size_t ws_size,
                              hipStream_t stream) {
    const float* x    = (const float*)d_in[0];
    const float* w_dw = (const float*)d_in[1];
    const float* g1   = (const float*)d_in[2];
    const float* be1  = (const float*)d_in[3];
    const float* mu1  = (const float*)d_in[4];
    const float* va1  = (const float*)d_in[5];
    const float* w1   = (const float*)d_in[6];
    const float* b1   = (const float*)d_in[7];
    const float* g2   = (const float*)d_in[8];
    const float* be2  = (const float*)d_in[9];
    const float* mu2  = (const float*)d_in[10];
    const float* va2  = (const float*)d_in[11];
    const float* w2   = (const float*)d_in[12];
    const float* b2   = (const float*)d_in[13];
    const float* alp  = (const float*)d_in[14];
    float* out = (float*)d_out;
    float* y1  = (float*)d_ws;   // B*C*DD*H*W*4 = 16 MiB of scratch

    dwconv_kernel<<<(B * DD * C) / 2, 256, 0, stream>>>(x, w_dw, g1, be1, mu1, va1, y1);
    fuse_kernel<<<(B * DD * H * W) / 256, 256, 0, stream>>>(
        x, y1, w1, b1, g2, be2, mu2, va2, w2, b2, alp, out);
}